// Round 1
// baseline (381.317 us; speedup 1.0000x reference)
//
#include <hip/hip_runtime.h>
#include <hip/hip_bf16.h>

// Problem constants
#define NN 384
#define HD 128
#define RB 16
#define CUTOFF2 144.0f
#define GAMMA 1.7777778f   // (16/12)^2
#define MU_STEP 0.8f       // 12/15

// ws layout (float units)
#define WS_XA 0
#define WS_XB 1152
#define WS_H  2304
#define WS_A  51456
#define WS_B  100608
#define WS_AGG 149760
#define WS_PK  198912      // unsigned view, 3*17920

#define PK_PER_LAYER 17920 // 8448 (w2t) + 8448 (c1t) + 1024 (wep)
#define W2T_U32 8448       // 64 pairs * (128 + 4 pad) k
#define WEP_OFF 16896

#define EDGE_SMEM 78592

__device__ __forceinline__ float blo(unsigned u){ return __uint_as_float(u << 16); }
__device__ __forceinline__ float bhi(unsigned u){ return __uint_as_float(u & 0xffff0000u); }
__device__ __forceinline__ unsigned short f2bf(float f){
  unsigned u = __float_as_uint(f);
  return (unsigned short)((u + 0x7fffu + ((u >> 16) & 1u)) >> 16);  // RNE
}
__device__ __forceinline__ float silu(float x){ return x / (1.0f + __expf(-x)); }

// ---- pack weights to bf16 pairs: w2t/c1t transposed-padded [p=64][k=132], wep [k=16][p=64]
__global__ void k_prep(const float* __restrict__ eW1, const float* __restrict__ eW2,
                       const float* __restrict__ cW1, unsigned* __restrict__ pk){
  int t = blockIdx.x * 256 + threadIdx.x;
  if (t >= 3 * PK_PER_LAYER) return;
  int l = t / PK_PER_LAYER, r = t % PK_PER_LAYER;
  unsigned val = 0;
  if (r < W2T_U32) {
    int p = r / 132, k = r % 132;
    if (k < 128) {
      const float* src = eW2 + (l * 128 + k) * 128 + 2 * p;
      val = ((unsigned)f2bf(src[1]) << 16) | f2bf(src[0]);
    }
  } else if (r < 2 * W2T_U32) {
    int rr = r - W2T_U32; int p = rr / 132, k = rr % 132;
    if (k < 128) {
      const float* src = cW1 + (l * 128 + k) * 128 + 2 * p;
      val = ((unsigned)f2bf(src[1]) << 16) | f2bf(src[0]);
    }
  } else {
    int rr = r - WEP_OFF; int k = rr / 64, p = rr % 64;
    const float* src = eW1 + (l * 272 + 256 + k) * 128 + 2 * p;
    val = ((unsigned)f2bf(src[1]) << 16) | f2bf(src[0]);
  }
  pk[t] = val;
}

// ---- center coords, seed both x buffers
__global__ void k_center(const float* __restrict__ anchor, float* __restrict__ xA,
                         float* __restrict__ xB){
  __shared__ float ssum[3];
  int t = threadIdx.x;
  if (t < 3) ssum[t] = 0.f;
  __syncthreads();
  float v0 = anchor[t*3], v1 = anchor[t*3+1], v2 = anchor[t*3+2];
  atomicAdd(&ssum[0], v0); atomicAdd(&ssum[1], v1); atomicAdd(&ssum[2], v2);
  __syncthreads();
  float m0 = ssum[0]*(1.f/384.f), m1 = ssum[1]*(1.f/384.f), m2 = ssum[2]*(1.f/384.f);
  xA[t*3]=v0-m0; xA[t*3+1]=v1-m1; xA[t*3+2]=v2-m2;
  xB[t*3]=v0-m0; xB[t*3+1]=v1-m1; xB[t*3+2]=v2-m2;
}

// ---- h = z@projW + b; A/B = h@eW1[l=0] halves (+eb1 folded into A); zero agg
__global__ void k_projAB(const float* __restrict__ z, const float* __restrict__ pW,
                         const float* __restrict__ pb, const float* __restrict__ eW1,
                         const float* __restrict__ eb1, float* __restrict__ h,
                         float* __restrict__ A, float* __restrict__ Bm, float* __restrict__ agg){
  __shared__ float sz[64]; __shared__ float sh[128];
  int i = blockIdx.x, o = threadIdx.x;
  if (o < 64) sz[o] = z[i*64 + o];
  __syncthreads();
  float hh = pb[o];
  #pragma unroll 8
  for (int k = 0; k < 64; ++k) hh += sz[k] * pW[k*128 + o];
  h[i*128 + o] = hh; sh[o] = hh; agg[i*128 + o] = 0.f;
  __syncthreads();
  float aa = eb1[o], bb = 0.f;
  for (int k = 0; k < 128; ++k) { float hv = sh[k]; aa += hv*eW1[k*128+o]; bb += hv*eW1[(128+k)*128+o]; }
  A[i*128 + o] = aa; Bm[i*128 + o] = bb;
}

// ---- node update (layer l), then A/B for layer l+1; zero agg; seed xdst = xsrc
__global__ void k_nodeAB(const float* __restrict__ nW1, const float* __restrict__ nb1,
                         const float* __restrict__ nW2, const float* __restrict__ nb2,
                         const float* __restrict__ eW1n, const float* __restrict__ eb1n,
                         float* __restrict__ h, float* __restrict__ agg,
                         float* __restrict__ A, float* __restrict__ Bm,
                         const float* __restrict__ xsrc, float* __restrict__ xdst){
  __shared__ float sh[128], sg[128], st[128], shn[128];
  int i = blockIdx.x, o = threadIdx.x;
  sh[o] = h[i*128 + o]; sg[o] = agg[i*128 + o]; agg[i*128 + o] = 0.f;
  if (o < 3) xdst[i*3 + o] = xsrc[i*3 + o];
  __syncthreads();
  float a = nb1[o];
  for (int k = 0; k < 128; ++k) a += sh[k] * nW1[k*128 + o];
  for (int k = 0; k < 128; ++k) a += sg[k] * nW1[(128 + k)*128 + o];
  st[o] = silu(a);
  __syncthreads();
  float hn = sh[o] + nb2[o];
  for (int k = 0; k < 128; ++k) hn += st[k] * nW2[k*128 + o];
  h[i*128 + o] = hn; shn[o] = hn;
  __syncthreads();
  float aa = eb1n[o], bb = 0.f;
  for (int k = 0; k < 128; ++k) { float hv = shn[k]; aa += hv*eW1n[k*128+o]; bb += hv*eW1n[(128+k)*128+o]; }
  A[i*128 + o] = aa; Bm[i*128 + o] = bb;
}

// ---- edge kernel: block = (receiver i, half j-range); each wave streams its own edges
__global__ __launch_bounds__(256, 2) void k_edge(
    const float* __restrict__ x_in, float* __restrict__ x_out,
    const float* __restrict__ A, const float* __restrict__ Bm,
    float* __restrict__ agg, const unsigned* __restrict__ pkl,
    const float* __restrict__ eb2g, const float* __restrict__ cb1g,
    const float* __restrict__ cw2g){
  extern __shared__ char smem_raw[];
  unsigned* w2t = (unsigned*)smem_raw;      // 8448
  unsigned* c1t = w2t + 8448;               // 8448
  unsigned* wep = c1t + 8448;               // 1024
  float* sAi  = (float*)(wep + 1024);       // 128 (A row incl eb1)
  float* seb2 = sAi + 128;
  float* scb1 = seb2 + 128;
  float* scw2 = scb1 + 128;
  float* sm1  = scw2 + 128;                 // 4*128 (per-wave slices)
  float* smm  = sm1 + 512;                  // 4*128
  float* se   = smm + 512;                  // 4*16
  float* sdx  = se + 64;                    // 12
  int* scount = (int*)(sdx + 12);
  unsigned short* slist = (unsigned short*)(scount + 1); // 192

  const int tid = threadIdx.x;
  const int i = blockIdx.x >> 1;
  const int jlo = (blockIdx.x & 1) * 192;
  const int q = tid & 63, s = tid >> 6;     // lane, wave

  for (int idx = tid; idx < PK_PER_LAYER; idx += 256)
    ((unsigned*)smem_raw)[idx] = pkl[idx];
  if (tid < 128) {
    sAi[tid]  = A[i*128 + tid];
    seb2[tid] = eb2g[tid];
    scb1[tid] = cb1g[tid];
    scw2[tid] = cw2g[tid];
  }
  if (tid == 0) *scount = 0;
  __syncthreads();

  const float xi0 = x_in[i*3], xi1 = x_in[i*3+1], xi2 = x_in[i*3+2];
  if (tid < 192) {
    int j = jlo + tid;
    float d0 = xi0 - x_in[j*3], d1 = xi1 - x_in[j*3+1], d2c = xi2 - x_in[j*3+2];
    float dd = d0*d0 + d1*d1 + d2c*d2c;
    bool msk = ((dd < CUTOFF2) && (j != i)) || (j == i-1) || (j == i+1);
    if (msk) { int slot = atomicAdd(scount, 1); slist[slot] = (unsigned short)j; }
  }
  __syncthreads();
  const int nact = *scount;

  float aggp0 = 0.f, aggp1 = 0.f;
  float dxw0 = 0.f, dxw1 = 0.f, dxw2 = 0.f;
  const unsigned* wrC = w2t + q*132;
  const unsigned* wrD = c1t + q*132;
  float* m1s = sm1 + s*128;
  float* mms = smm + s*128;
  float* ses = se + s*16;

  for (int e = s; e < nact; e += 4) {       // wave-private stream, no barriers
    const int j = (int)slist[e];
    const float xj0 = x_in[j*3], xj1 = x_in[j*3+1], xj2 = x_in[j*3+2];
    const float ddx0 = xi0-xj0, ddx1 = xi1-xj1, ddx2 = xi2-xj2;
    const float d2v = ddx0*ddx0 + ddx1*ddx1 + ddx2*ddx2;
    const float d = sqrtf(d2v);
    if (q < RB) { float tt = d - MU_STEP*(float)q; ses[q] = __expf(-GAMMA*tt*tt); }
    const float2 bj = *(const float2*)(Bm + j*128 + 2*q);
    __threadfence_block();                  // in-wave DS order: ses write -> read

    // m1 = silu(A_i + B_j + e@We + eb1)   (eb1 folded into A)
    float accA = sAi[2*q]   + bj.x;
    float accB = sAi[2*q+1] + bj.y;
    #pragma unroll
    for (int k = 0; k < RB; ++k) {
      unsigned u = wep[k*64 + q]; float ev = ses[k];
      accA += ev * blo(u); accB += ev * bhi(u);
    }
    ((float2*)m1s)[q] = make_float2(silu(accA), silu(accB));
    __threadfence_block();

    // m = silu(m1 @ eW2 + eb2)
    float a0=0.f, a1=0.f, a2=0.f, a3=0.f;
    #pragma unroll
    for (int k4 = 0; k4 < 32; ++k4) {
      const uint4 w4 = *(const uint4*)(wrC + k4*4);
      const float4 m4 = *(const float4*)(m1s + k4*4);
      a0 += m4.x*blo(w4.x); a1 += m4.x*bhi(w4.x);
      a0 += m4.y*blo(w4.y); a1 += m4.y*bhi(w4.y);
      a2 += m4.z*blo(w4.z); a3 += m4.z*bhi(w4.z);
      a2 += m4.w*blo(w4.w); a3 += m4.w*bhi(w4.w);
    }
    float mm0 = silu(seb2[2*q]   + a0 + a2);
    float mm1 = silu(seb2[2*q+1] + a1 + a3);
    ((float2*)mms)[q] = make_float2(mm0, mm1);
    aggp0 += mm0; aggp1 += mm1;
    __threadfence_block();

    // c1 = silu(m @ cW1 + cb1); w = c1 . cW2
    a0=0.f; a1=0.f; a2=0.f; a3=0.f;
    #pragma unroll
    for (int k4 = 0; k4 < 32; ++k4) {
      const uint4 w4 = *(const uint4*)(wrD + k4*4);
      const float4 m4 = *(const float4*)(mms + k4*4);
      a0 += m4.x*blo(w4.x); a1 += m4.x*bhi(w4.x);
      a0 += m4.y*blo(w4.y); a1 += m4.y*bhi(w4.y);
      a2 += m4.z*blo(w4.z); a3 += m4.z*bhi(w4.z);
      a2 += m4.w*blo(w4.w); a3 += m4.w*bhi(w4.w);
    }
    float c0  = silu(scb1[2*q]   + a0 + a2);
    float c1v = silu(scb1[2*q+1] + a1 + a3);
    float p = c0*scw2[2*q] + c1v*scw2[2*q+1];
    #pragma unroll
    for (int off = 32; off; off >>= 1) p += __shfl_xor(p, off);
    if (q == 0) { dxw0 += p*ddx0; dxw1 += p*ddx1; dxw2 += p*ddx2; }
  }

  // epilogue: combine 4 wave slices
  ((float2*)m1s)[q] = make_float2(aggp0, aggp1);
  if (q == 0) { sdx[s*3] = dxw0; sdx[s*3+1] = dxw1; sdx[s*3+2] = dxw2; }
  __syncthreads();
  if (tid < 128)
    atomicAdd(&agg[i*128 + tid], sm1[tid] + sm1[128+tid] + sm1[256+tid] + sm1[384+tid]);
  if (tid < 3)
    atomicAdd(&x_out[i*3 + tid], sdx[tid] + sdx[3+tid] + sdx[6+tid] + sdx[9+tid]);
}

extern "C" void kernel_launch(void* const* d_in, const int* in_sizes, int n_in,
                              void* d_out, int out_size, void* d_ws, size_t ws_size,
                              hipStream_t stream){
  const float* z      = (const float*)d_in[0];
  const float* anchor = (const float*)d_in[1];
  const float* projW  = (const float*)d_in[2];
  const float* projb  = (const float*)d_in[3];
  const float* eW1    = (const float*)d_in[4];
  const float* eb1    = (const float*)d_in[5];
  const float* eW2    = (const float*)d_in[6];
  const float* eb2    = (const float*)d_in[7];
  const float* nW1    = (const float*)d_in[8];
  const float* nb1    = (const float*)d_in[9];
  const float* nW2    = (const float*)d_in[10];
  const float* nb2    = (const float*)d_in[11];
  const float* cW1    = (const float*)d_in[12];
  const float* cb1    = (const float*)d_in[13];
  const float* cW2    = (const float*)d_in[14];
  float* out = (float*)d_out;

  float* ws = (float*)d_ws;
  float* xA  = ws + WS_XA;
  float* xB  = ws + WS_XB;
  float* h   = ws + WS_H;
  float* A   = ws + WS_A;
  float* Bm  = ws + WS_B;
  float* agg = ws + WS_AGG;
  unsigned* pk = (unsigned*)(ws + WS_PK);

  hipFuncSetAttribute((const void*)k_edge, hipFuncAttributeMaxDynamicSharedMemorySize, EDGE_SMEM);

  k_prep<<<210, 256, 0, stream>>>(eW1, eW2, cW1, pk);
  k_center<<<1, 384, 0, stream>>>(anchor, xA, xB);
  k_projAB<<<384, 128, 0, stream>>>(z, projW, projb, eW1, eb1, h, A, Bm, agg);

  // layer 0: read xA, accumulate into xB (seeded by k_center)
  k_edge<<<768, 256, EDGE_SMEM, stream>>>(xA, xB, A, Bm, agg, pk, eb2, cb1, cW2);
  k_nodeAB<<<384, 128, 0, stream>>>(nW1, nb1, nW2, nb2,
                                    eW1 + 272*128, eb1 + 128,
                                    h, agg, A, Bm, xB, xA);
  // layer 1: read xB, accumulate into xA (seeded by nodeAB)
  k_edge<<<768, 256, EDGE_SMEM, stream>>>(xB, xA, A, Bm, agg, pk + PK_PER_LAYER,
                                          eb2 + 128, cb1 + 128, cW2 + 128);
  k_nodeAB<<<384, 128, 0, stream>>>(nW1 + 256*128, nb1 + 128, nW2 + 128*128, nb2 + 128,
                                    eW1 + 2*272*128, eb1 + 256,
                                    h, agg, A, Bm, xA, out);
  // layer 2: read xA, accumulate into out (seeded by nodeAB)
  k_edge<<<768, 256, EDGE_SMEM, stream>>>(xA, out, A, Bm, agg, pk + 2*PK_PER_LAYER,
                                          eb2 + 256, cb1 + 256, cW2 + 256);
}

// Round 2
// 251.364 us; speedup vs baseline: 1.5170x; 1.5170x over previous
//
#include <hip/hip_runtime.h>
#include <hip/hip_bf16.h>

// Problem constants
#define NN 384
#define CUTOFF2 144.0f
#define GAMMA 1.7777778f   // (16/12)^2

// packed B-frag layout per layer (u32 units): [W1b 8192 | We 2048 | W2 8192 | C1 8192]
#define PK_L 26624
#define PK_WE 8192
#define PK_W2 10240
#define PK_C1 18432

#define G_EDGE 128
#define EDGE_SMEM 141312   // 26624*4 weights + 8*4352 per-wave stage

// ws byte offsets
#define O_XA 0
#define O_XB 4608
#define O_H 9216
#define O_A 205824
#define O_AGG 402432
#define O_HBF 599040
#define O_ELIST 697344
#define O_CNT 992256
#define O_UCNT 993792
#define O_UNITS 993856
#define O_PK 1034816

typedef __bf16 bf16x8 __attribute__((ext_vector_type(8)));
typedef float f32x4 __attribute__((ext_vector_type(4)));

__device__ __forceinline__ unsigned short f2bf(float f){
  unsigned u = __float_as_uint(f);
  return (unsigned short)((u + 0x7fffu + ((u >> 16) & 1u)) >> 16);  // RNE
}
__device__ __forceinline__ float silu(float x){ return x / (1.0f + __expf(-x)); }

// ---- pack weights into MFMA B-fragment order (bf16 pairs), 3 layers
// B-frag for 16x16x32: lane l holds W[k = c*32 + (l>>4)*8 + t][n = ntile*16 + (l&15)], t=0..7
__global__ void k_prep(const float* __restrict__ eW1, const float* __restrict__ eW2,
                       const float* __restrict__ cW1, unsigned* __restrict__ pk){
  int t = blockIdx.x * 256 + threadIdx.x;
  if (t >= 3 * PK_L) return;
  int layer = t / PK_L, r = t % PK_L;
  const float* src; int fr; int isWe = 0;
  if (r < PK_WE)        { fr = r;          src = eW1 + (layer*272 + 128)*128; }
  else if (r < PK_W2)   { fr = r - PK_WE;  src = eW1 + (layer*272 + 256)*128; isWe = 1; }
  else if (r < PK_C1)   { fr = r - PK_W2;  src = eW2 + layer*128*128; }
  else                  { fr = r - PK_C1;  src = cW1 + layer*128*128; }
  int tp = fr & 3, l = (fr >> 2) & 63, nc = fr >> 8;
  int n, k;
  if (!isWe) { n = nc >> 2; int c = nc & 3; k = c*32 + ((l>>4)<<3) + 2*tp; }
  else       { n = nc;                      k = ((l>>4)<<3) + 2*tp; }
  int nn = n*16 + (l & 15);
  float w0, w1;
  if (isWe) { w0 = (k < 16)   ? src[k*128+nn]     : 0.f;
              w1 = (k+1 < 16) ? src[(k+1)*128+nn] : 0.f; }
  else      { w0 = src[k*128+nn]; w1 = src[(k+1)*128+nn]; }
  pk[t] = ((unsigned)f2bf(w1) << 16) | f2bf(w0);
}

// ---- center coords, seed both x buffers
__global__ void k_center(const float* __restrict__ anchor, float* __restrict__ xA,
                         float* __restrict__ xB){
  __shared__ float ssum[3];
  int t = threadIdx.x;
  if (t < 3) ssum[t] = 0.f;
  __syncthreads();
  float v0 = anchor[t*3], v1 = anchor[t*3+1], v2 = anchor[t*3+2];
  atomicAdd(&ssum[0], v0); atomicAdd(&ssum[1], v1); atomicAdd(&ssum[2], v2);
  __syncthreads();
  float m0 = ssum[0]*(1.f/384.f), m1 = ssum[1]*(1.f/384.f), m2 = ssum[2]*(1.f/384.f);
  xA[t*3]=v0-m0; xA[t*3+1]=v1-m1; xA[t*3+2]=v2-m2;
  xB[t*3]=v0-m0; xB[t*3+1]=v1-m1; xB[t*3+2]=v2-m2;
}

// ---- h = z@projW + b; hbf = bf16(h); A = h@W1a + eb1; zero agg
__global__ void k_projAB(const float* __restrict__ z, const float* __restrict__ pW,
                         const float* __restrict__ pb, const float* __restrict__ eW1,
                         const float* __restrict__ eb1, float* __restrict__ h,
                         unsigned short* __restrict__ hbf, float* __restrict__ A,
                         float* __restrict__ agg){
  __shared__ float sz[64]; __shared__ float sh[128];
  int i = blockIdx.x, o = threadIdx.x;
  if (o < 64) sz[o] = z[i*64 + o];
  __syncthreads();
  float hh = pb[o];
  #pragma unroll 8
  for (int k = 0; k < 64; ++k) hh += sz[k] * pW[k*128 + o];
  h[i*128 + o] = hh; hbf[i*128 + o] = f2bf(hh); sh[o] = hh; agg[i*128 + o] = 0.f;
  __syncthreads();
  float aa = eb1[o];
  for (int k = 0; k < 128; ++k) aa += sh[k] * eW1[k*128 + o];
  A[i*128 + o] = aa;
}

// ---- node update (layer l), then A/hbf for layer l+1; zero agg; seed xdst = xsrc
__global__ void k_nodeAB(const float* __restrict__ nW1, const float* __restrict__ nb1,
                         const float* __restrict__ nW2, const float* __restrict__ nb2,
                         const float* __restrict__ eW1n, const float* __restrict__ eb1n,
                         float* __restrict__ h, unsigned short* __restrict__ hbf,
                         float* __restrict__ agg, float* __restrict__ A,
                         const float* __restrict__ xsrc, float* __restrict__ xdst){
  __shared__ float sh[128], sg[128], st[128], shn[128];
  int i = blockIdx.x, o = threadIdx.x;
  sh[o] = h[i*128 + o]; sg[o] = agg[i*128 + o]; agg[i*128 + o] = 0.f;
  if (o < 3) xdst[i*3 + o] = xsrc[i*3 + o];
  __syncthreads();
  float a = nb1[o];
  for (int k = 0; k < 128; ++k) a += sh[k] * nW1[k*128 + o];
  for (int k = 0; k < 128; ++k) a += sg[k] * nW1[(128 + k)*128 + o];
  st[o] = silu(a);
  __syncthreads();
  float hn = sh[o] + nb2[o];
  for (int k = 0; k < 128; ++k) hn += st[k] * nW2[k*128 + o];
  h[i*128 + o] = hn; hbf[i*128 + o] = f2bf(hn); shn[o] = hn;
  __syncthreads();
  float aa = eb1n[o];
  for (int k = 0; k < 128; ++k) aa += shn[k] * eW1n[k*128 + o];
  A[i*128 + o] = aa;
}

// ---- build per-receiver compacted edge lists (padded to x16 with j=i)
__global__ void k_scan(const float* __restrict__ x, unsigned short* __restrict__ elist,
                       int* __restrict__ counts){
  __shared__ int scnt; __shared__ float xi[3];
  int i = blockIdx.x, j = threadIdx.x;
  if (j == 0) scnt = 0;
  if (j < 3) xi[j] = x[i*3 + j];
  __syncthreads();
  float d0 = xi[0]-x[j*3], d1 = xi[1]-x[j*3+1], d2 = xi[2]-x[j*3+2];
  float dd = d0*d0 + d1*d1 + d2*d2;
  bool msk = ((dd < CUTOFF2) && (j != i)) || (j == i-1) || (j == i+1);
  if (msk) { int s = atomicAdd(&scnt, 1); elist[i*384 + s] = (unsigned short)j; }
  __syncthreads();
  int cnt = scnt;
  int pad = (16 - (cnt & 15)) & 15;
  if (j < pad) elist[i*384 + cnt + j] = (unsigned short)i;
  if (j == 0) counts[i] = cnt;
}

// ---- prefix-sum unit table: unit = (i | batch<<16)
__global__ void k_units(const int* __restrict__ counts, int* __restrict__ units,
                        int* __restrict__ Ucnt){
  __shared__ int sv[512];
  int t = threadIdx.x;
  int u = (t < 384) ? ((counts[t] + 15) >> 4) : 0;
  sv[t] = u; __syncthreads();
  for (int off = 1; off < 512; off <<= 1) {
    int add = (t >= off) ? sv[t - off] : 0;
    __syncthreads();
    sv[t] += add;
    __syncthreads();
  }
  int base = sv[t] - u;
  for (int b = 0; b < u; ++b) units[base + b] = t | (b << 16);
  if (t == 511) Ucnt[0] = sv[511];
}

// ---- MFMA edge kernel: wave = one unit (16 same-receiver edges)
__global__ __launch_bounds__(512, 1) void k_edge(
    const float* __restrict__ x_in, float* __restrict__ x_out,
    const float* __restrict__ Ag, const unsigned short* __restrict__ hbf,
    const unsigned short* __restrict__ elist, const int* __restrict__ counts,
    const int* __restrict__ units, const int* __restrict__ Ucnt,
    float* __restrict__ agg, const unsigned* __restrict__ pkl,
    const float* __restrict__ eb2g, const float* __restrict__ cb1g,
    const float* __restrict__ cw2g){
  extern __shared__ unsigned smem[];
  const int tid = threadIdx.x, q = tid & 63, s = tid >> 6;
  // stage packed weight fragments (contiguous 104 KB)
  for (int idx = tid; idx < PK_L/4; idx += 512)
    ((uint4*)smem)[idx] = ((const uint4*)pkl)[idx];
  __syncthreads();

  const int col0 = q & 15, quad = q >> 4;
  float eb2v[8], cb1v[8], cw2v[8];
  #pragma unroll
  for (int t = 0; t < 8; ++t) {
    int c = t*16 + col0;
    eb2v[t] = eb2g[c]; cb1v[t] = cb1g[c]; cw2v[t] = cw2g[c];
  }
  unsigned short* stg = (unsigned short*)(smem + PK_L + s*1088);  // 16 x 136 bf16
  const int U = Ucnt[0];
  const f32x4 z4 = {0.f, 0.f, 0.f, 0.f};
  union { uint4 u; bf16x8 v; } cva, cve;

  for (int u = blockIdx.x*8 + s; u < U; u += G_EDGE*8) {
    const int desc = units[u];
    const int i = desc & 0xffff, b = desc >> 16;
    const int cnt = counts[i];
    int nvalid = cnt - b*16; if (nvalid > 16) nvalid = 16;
    const int j = (int)elist[i*384 + b*16 + col0];

    const float xi0 = x_in[i*3], xi1 = x_in[i*3+1], xi2 = x_in[i*3+2];
    const float df0 = xi0 - x_in[j*3], df1 = xi1 - x_in[j*3+1], df2 = xi2 - x_in[j*3+2];
    const float d = sqrtf(df0*df0 + df1*df1 + df2*df2);

    // RBF A-frag (K padded 16->32 with zeros; matching We frags are zero)
    if (q < 32) {
      #pragma unroll
      for (int tp = 0; tp < 4; ++tp) {
        float k0 = (float)(quad*8 + 2*tp);
        float t0 = d - 0.8f*k0, t1 = d - 0.8f*(k0 + 1.f);
        float e0 = __expf(-GAMMA*t0*t0), e1 = __expf(-GAMMA*t1*t1);
        (&cve.u.x)[tp] = ((unsigned)f2bf(e1) << 16) | f2bf(e0);
      }
    } else cve.u = make_uint4(0u, 0u, 0u, 0u);

    // h_j A-frags straight from bf16 h (16B per chunk)
    uint4 ha[4];
    #pragma unroll
    for (int c = 0; c < 4; ++c)
      ha[c] = *(const uint4*)(hbf + j*128 + c*32 + quad*8);
    float Aval[8];
    #pragma unroll
    for (int t = 0; t < 8; ++t) Aval[t] = Ag[i*128 + t*16 + col0];

    // GEMM1: m1 = silu(h_j@W1b + e@We + A_i)   (A_i = h_i@W1a + eb1)
    f32x4 acc[8];
    #pragma unroll
    for (int t = 0; t < 8; ++t) acc[t] = z4;
    #pragma unroll
    for (int t = 0; t < 8; ++t) {
      #pragma unroll
      for (int c = 0; c < 4; ++c) {
        bf16x8 bf = *(const bf16x8*)(smem + ((t*4 + c)*64 + q)*4);
        cva.u = ha[c];
        acc[t] = __builtin_amdgcn_mfma_f32_16x16x32_bf16(cva.v, bf, acc[t], 0, 0, 0);
      }
      bf16x8 bw = *(const bf16x8*)(smem + PK_WE + (t*64 + q)*4);
      acc[t] = __builtin_amdgcn_mfma_f32_16x16x32_bf16(cve.v, bw, acc[t], 0, 0, 0);
    }
    #pragma unroll
    for (int t = 0; t < 8; ++t)
      #pragma unroll
      for (int r = 0; r < 4; ++r)
        stg[(quad*4 + r)*136 + t*16 + col0] = f2bf(silu(acc[t][r] + Aval[t]));
    __threadfence_block();

    bf16x8 a2[4];
    #pragma unroll
    for (int c = 0; c < 4; ++c)
      a2[c] = *(const bf16x8*)((const char*)stg + (col0*136 + c*32 + quad*8)*2);
    __threadfence_block();

    // GEMM2: m = silu(m1@eW2 + eb2)
    f32x4 acc2[8];
    #pragma unroll
    for (int t = 0; t < 8; ++t) acc2[t] = z4;
    #pragma unroll
    for (int t = 0; t < 8; ++t)
      #pragma unroll
      for (int c = 0; c < 4; ++c) {
        bf16x8 bf = *(const bf16x8*)(smem + PK_W2 + ((t*4 + c)*64 + q)*4);
        acc2[t] = __builtin_amdgcn_mfma_f32_16x16x32_bf16(a2[c], bf, acc2[t], 0, 0, 0);
      }
    float colsum[8];
    #pragma unroll
    for (int t = 0; t < 8; ++t) {
      float cs = 0.f;
      #pragma unroll
      for (int r = 0; r < 4; ++r) {
        float mv = silu(acc2[t][r] + eb2v[t]);
        stg[(quad*4 + r)*136 + t*16 + col0] = f2bf(mv);
        if (quad*4 + r < nvalid) cs += mv;
      }
      cs += __shfl_xor(cs, 16); cs += __shfl_xor(cs, 32);
      colsum[t] = cs;
    }
    __threadfence_block();
    bf16x8 a3[4];
    #pragma unroll
    for (int c = 0; c < 4; ++c)
      a3[c] = *(const bf16x8*)((const char*)stg + (col0*136 + c*32 + quad*8)*2);
    __threadfence_block();
    if (q < 16) {
      #pragma unroll
      for (int t = 0; t < 8; ++t) atomicAdd(&agg[i*128 + t*16 + q], colsum[t]);
    }

    // GEMM3: c1 = silu(m@cW1 + cb1); w_row = c1 . cW2
    f32x4 acc3[8];
    #pragma unroll
    for (int t = 0; t < 8; ++t) acc3[t] = z4;
    #pragma unroll
    for (int t = 0; t < 8; ++t)
      #pragma unroll
      for (int c = 0; c < 4; ++c) {
        bf16x8 bf = *(const bf16x8*)(smem + PK_C1 + ((t*4 + c)*64 + q)*4);
        acc3[t] = __builtin_amdgcn_mfma_f32_16x16x32_bf16(a3[c], bf, acc3[t], 0, 0, 0);
      }
    float p0 = 0.f, p1 = 0.f, p2 = 0.f, p3 = 0.f;
    #pragma unroll
    for (int t = 0; t < 8; ++t) {
      p0 += silu(acc3[t][0] + cb1v[t]) * cw2v[t];
      p1 += silu(acc3[t][1] + cb1v[t]) * cw2v[t];
      p2 += silu(acc3[t][2] + cb1v[t]) * cw2v[t];
      p3 += silu(acc3[t][3] + cb1v[t]) * cw2v[t];
    }
    #pragma unroll
    for (int off = 1; off < 16; off <<= 1) {
      p0 += __shfl_xor(p0, off); p1 += __shfl_xor(p1, off);
      p2 += __shfl_xor(p2, off); p3 += __shfl_xor(p3, off);
    }
    // dx_i = sum over valid rows of w_row * diff_row
    float dxa = 0.f;
    #pragma unroll
    for (int r = 0; r < 4; ++r) {
      int row = quad*4 + r;
      float s0 = __shfl(df0, row), s1 = __shfl(df1, row), s2 = __shfl(df2, row);
      float dv = (col0 == 0) ? s0 : (col0 == 1) ? s1 : s2;
      float wr = (r == 0) ? p0 : (r == 1) ? p1 : (r == 2) ? p2 : p3;
      if (row < nvalid && col0 < 3) dxa += wr * dv;
    }
    dxa += __shfl_xor(dxa, 16); dxa += __shfl_xor(dxa, 32);
    if (q < 3) atomicAdd(&x_out[i*3 + q], dxa);
  }
}

extern "C" void kernel_launch(void* const* d_in, const int* in_sizes, int n_in,
                              void* d_out, int out_size, void* d_ws, size_t ws_size,
                              hipStream_t stream){
  const float* z      = (const float*)d_in[0];
  const float* anchor = (const float*)d_in[1];
  const float* projW  = (const float*)d_in[2];
  const float* projb  = (const float*)d_in[3];
  const float* eW1    = (const float*)d_in[4];
  const float* eb1    = (const float*)d_in[5];
  const float* eW2    = (const float*)d_in[6];
  const float* eb2    = (const float*)d_in[7];
  const float* nW1    = (const float*)d_in[8];
  const float* nb1    = (const float*)d_in[9];
  const float* nW2    = (const float*)d_in[10];
  const float* nb2    = (const float*)d_in[11];
  const float* cW1    = (const float*)d_in[12];
  const float* cb1    = (const float*)d_in[13];
  const float* cW2    = (const float*)d_in[14];
  float* out = (float*)d_out;

  char* w = (char*)d_ws;
  float* xA  = (float*)(w + O_XA);
  float* xB  = (float*)(w + O_XB);
  float* h   = (float*)(w + O_H);
  float* A   = (float*)(w + O_A);
  float* agg = (float*)(w + O_AGG);
  unsigned short* hbf   = (unsigned short*)(w + O_HBF);
  unsigned short* elist = (unsigned short*)(w + O_ELIST);
  int* counts = (int*)(w + O_CNT);
  int* Ucnt   = (int*)(w + O_UCNT);
  int* units  = (int*)(w + O_UNITS);
  unsigned* pk = (unsigned*)(w + O_PK);

  hipFuncSetAttribute((const void*)k_edge, hipFuncAttributeMaxDynamicSharedMemorySize, EDGE_SMEM);

  k_prep<<<312, 256, 0, stream>>>(eW1, eW2, cW1, pk);
  k_center<<<1, 384, 0, stream>>>(anchor, xA, xB);
  k_projAB<<<384, 128, 0, stream>>>(z, projW, projb, eW1, eb1, h, hbf, A, agg);

  // layer 0: read xA, accumulate into xB (seeded by k_center)
  k_scan<<<384, 384, 0, stream>>>(xA, elist, counts);
  k_units<<<1, 512, 0, stream>>>(counts, units, Ucnt);
  k_edge<<<G_EDGE, 512, EDGE_SMEM, stream>>>(xA, xB, A, hbf, elist, counts, units, Ucnt,
                                             agg, pk, eb2, cb1, cW2);
  k_nodeAB<<<384, 128, 0, stream>>>(nW1, nb1, nW2, nb2,
                                    eW1 + 272*128, eb1 + 128,
                                    h, hbf, agg, A, xB, xA);
  // layer 1: read xB, accumulate into xA
  k_scan<<<384, 384, 0, stream>>>(xB, elist, counts);
  k_units<<<1, 512, 0, stream>>>(counts, units, Ucnt);
  k_edge<<<G_EDGE, 512, EDGE_SMEM, stream>>>(xB, xA, A, hbf, elist, counts, units, Ucnt,
                                             agg, pk + PK_L, eb2 + 128, cb1 + 128, cW2 + 128);
  k_nodeAB<<<384, 128, 0, stream>>>(nW1 + 256*128, nb1 + 128, nW2 + 128*128, nb2 + 128,
                                    eW1 + 2*272*128, eb1 + 256,
                                    h, hbf, agg, A, xA, out);
  // layer 2: read xA, accumulate into out
  k_scan<<<384, 384, 0, stream>>>(xA, elist, counts);
  k_units<<<1, 512, 0, stream>>>(counts, units, Ucnt);
  k_edge<<<G_EDGE, 512, EDGE_SMEM, stream>>>(xA, out, A, hbf, elist, counts, units, Ucnt,
                                             agg, pk + 2*PK_L, eb2 + 256, cb1 + 256, cW2 + 256);
}